// Round 1
// 259.115 us; speedup vs baseline: 1.0005x; 1.0005x over previous
//
#include <hip/hip_runtime.h>
#include <math.h>

#define N_SYM 128
#define BATCH 131072
#define B4    (BATCH / 4)   // row stride in float4 units = 32768
#define LEV   30.0f
#define D     8             // ring depth (iterations of prefetch ahead)

typedef float v4 __attribute__((ext_vector_type(4)));

// 4 columns per thread via float4 (dwordx4) accesses.
// R0-R2: dword-per-lane caps at ~1.75 TB/s (request-pacing-saturated at
// 256 B/request) regardless of prefetch depth. R3 (this round): request
// pacing model says the CU services ~1 wave-request per ~100-140 cy
// regardless of size; at 2 waves/CU the v4 D=4 ring leaves the VMEM
// queue empty ~30% of the time (59 ns/req effective vs 41 ns/req
// saturated). D=8 doubles per-wave outstanding loads (16->32) and
// loosens every compiler waitcnt by 16 requests to keep the queue fed.
__device__ __forceinline__ float step1(float f, float e, float p, float m,
                                       float st, float mn, float mx,
                                       float* um)
{
    const float mrl = m * LEV;
    const float us  = *um * mrl;                // unused_size
    const float mps = fabsf(p) + us;            // max_pos_size
    const float adj = fminf((p * f > 0.0f) ? us : mps, 0.0f);
    const float nps = f * (mps - adj);

    float       a  = fabsf(nps);
    const float sg = copysignf(1.0f, nps);
    a = floorf(a / st) * st;
    a = (a < mn) ? 0.0f : a;
    a = fminf(a, mx);

    *um = (mps - a) / mrl;
    return e * (sg * a) + (1.0f - e) * p;
}

__global__ __launch_bounds__(64) void lle_scan_kernel(
    const float* __restrict__ frac,
    const float* __restrict__ exs,
    const float* __restrict__ pos,
    const float* __restrict__ mrate,
    const float* __restrict__ um0,
    const float* __restrict__ msm_min,
    const float* __restrict__ msm_step,
    const float* __restrict__ msm_max,
    float* __restrict__ out)
{
    const size_t c4 = (size_t)(blockIdx.x * 64 + threadIdx.x); // float4 col idx

    const v4* F = (const v4*)frac;
    const v4* E = (const v4*)exs;
    const v4* P = (const v4*)pos;
    const v4* M = (const v4*)mrate;
    v4*       O = (v4*)out;

    const v4 umv = __builtin_nontemporal_load((const v4*)um0 + c4);
    float um[4] = {umv.x, umv.y, umv.z, umv.w};

    v4 fb[D], eb[D], pb[D], mb[D];

    // warm the ring: symbols 0..D-1
#pragma unroll
    for (int j = 0; j < D; ++j) {
        const size_t o = (size_t)j * B4 + c4;
        fb[j] = __builtin_nontemporal_load(F + o);
        eb[j] = __builtin_nontemporal_load(E + o);
        pb[j] = __builtin_nontemporal_load(P + o);
        mb[j] = __builtin_nontemporal_load(M + o);
    }

    // hot loop: consume s = 0 .. N_SYM-D-1, refill slot with s+D
    for (int s0 = 0; s0 < N_SYM - D; s0 += D) {
#pragma unroll
        for (int j = 0; j < D; ++j) {
            const int s = s0 + j;
            const v4 f = fb[j];
            const v4 e = eb[j];
            const v4 p = pb[j];
            const v4 m = mb[j];

            {   // refill ring slot j with symbol s+D
                const size_t o = (size_t)(s + D) * B4 + c4;
                fb[j] = __builtin_nontemporal_load(F + o);
                eb[j] = __builtin_nontemporal_load(E + o);
                pb[j] = __builtin_nontemporal_load(P + o);
                mb[j] = __builtin_nontemporal_load(M + o);
            }

            const float st = msm_step[s];   // uniform -> s_load
            const float mn = msm_min[s];
            const float mx = msm_max[s];

            v4 r;
            r.x = step1(f.x, e.x, p.x, m.x, st, mn, mx, &um[0]);
            r.y = step1(f.y, e.y, p.y, m.y, st, mn, mx, &um[1]);
            r.z = step1(f.z, e.z, p.z, m.z, st, mn, mx, &um[2]);
            r.w = step1(f.w, e.w, p.w, m.w, st, mn, mx, &um[3]);

            __builtin_nontemporal_store(r, O + (size_t)s * B4 + c4);
        }
    }

    // peeled tail: last D symbols, no refill
#pragma unroll
    for (int j = 0; j < D; ++j) {
        const int s = N_SYM - D + j;
        const v4 f = fb[j];
        const v4 e = eb[j];
        const v4 p = pb[j];
        const v4 m = mb[j];

        const float st = msm_step[s];
        const float mn = msm_min[s];
        const float mx = msm_max[s];

        v4 r;
        r.x = step1(f.x, e.x, p.x, m.x, st, mn, mx, &um[0]);
        r.y = step1(f.y, e.y, p.y, m.y, st, mn, mx, &um[1]);
        r.z = step1(f.z, e.z, p.z, m.z, st, mn, mx, &um[2]);
        r.w = step1(f.w, e.w, p.w, m.w, st, mn, mx, &um[3]);

        __builtin_nontemporal_store(r, O + (size_t)s * B4 + c4);
    }

    v4 umo;
    umo.x = um[0]; umo.y = um[1]; umo.z = um[2]; umo.w = um[3];
    __builtin_nontemporal_store(umo, O + (size_t)N_SYM * B4 + c4);
}

extern "C" void kernel_launch(void* const* d_in, const int* in_sizes, int n_in,
                              void* d_out, int out_size, void* d_ws, size_t ws_size,
                              hipStream_t stream) {
    const float* frac     = (const float*)d_in[0];
    const float* exs      = (const float*)d_in[1];
    const float* pos      = (const float*)d_in[2];
    const float* mrate    = (const float*)d_in[3];
    const float* um0      = (const float*)d_in[4];
    const float* msm_min  = (const float*)d_in[5];
    const float* msm_step = (const float*)d_in[6];
    const float* msm_max  = (const float*)d_in[7];
    float* out = (float*)d_out;

    const int block = 64;
    const int grid  = (BATCH / 4) / block;   // 512 blocks, 1 wave each

    hipLaunchKernelGGL(lle_scan_kernel, dim3(grid), dim3(block), 0, stream,
                       frac, exs, pos, mrate, um0, msm_min, msm_step, msm_max,
                       out);
}